// Round 5
// baseline (90.242 us; speedup 1.0000x reference)
//
#include <hip/hip_runtime.h>

#define BA   8192
#define DE   8192
#define LGRP 2048   // DE/4 groups per row
#define TPB  256    // 4 waves per block; each wave owns 512 groups
#define NW   4      // waves per block
#define SEG  512    // groups per wave
#define NIT  8      // f32x4 loads per thread (SEG/64)
#define LPW  516    // LDS floats per wave segment (512 + 3 overlap + 1 pad)

typedef float f32x4 __attribute__((ext_vector_type(4)));

__global__ __launch_bounds__(TPB)
void multistrike_pool_kernel(const float* __restrict__ x, float* __restrict__ out) {
    __shared__ float b4s[NW][LPW];   // ~8.3 KB, wave-private -> no barrier

    const int row = blockIdx.x;
    const int wav = (int)threadIdx.x >> 6;
    const int lan = (int)threadIdx.x & 63;
    const int gbase = wav * SEG;

    const f32x4* __restrict__ xrow =
        reinterpret_cast<const f32x4*>(x + (size_t)row * DE);
    f32x4* __restrict__ orow =
        reinterpret_cast<f32x4*>(out + (size_t)row * DE);

    float* bseg = b4s[wav];

    f32x4 v[NIT];
    float b[NIT];

    // Pass 1: coalesced nt loads; block-of-4 sums into wave-private LDS.
    #pragma unroll
    for (int i = 0; i < NIT; ++i) {
        const int gl = i * 64 + lan;
        const f32x4 t = __builtin_nontemporal_load(&xrow[gbase + gl]);
        v[i] = t;
        b[i] = (t.x + t.y) + (t.z + t.w);
        bseg[gl] = b[i];
    }
    // Overlap: lanes 61-63 load next segment's first 3 groups (k=16 window).
    if (wav < NW - 1 && lan >= 61) {
        const f32x4 t = __builtin_nontemporal_load(&xrow[gbase + SEG + (lan - 61)]);
        bseg[SEG + (lan - 61)] = (t.x + t.y) + (t.z + t.w);
    }
    // No __syncthreads: same-wave DS write->read ordering via lgkmcnt.

    // Pass 2: combine registers + wave-private b4 neighbors, coalesced nt store.
    #pragma unroll
    for (int i = 0; i < NIT; ++i) {
        const int gl = i * 64 + lan;
        const int g  = gbase + gl;
        const f32x4 t = v[i];

        // normal path: own b4 from register + 3 LDS neighbor reads
        float s16 = b[i] + bseg[gl + 1] + bseg[gl + 2] + bseg[gl + 3];
        // boundary clamp (wave NW-1, last 3 groups): f2[g] = p16[g-4]
        if (g >= LGRP - 3) {
            s16 = (bseg[gl - 4] + bseg[gl - 3]) + (bseg[gl - 2] + bseg[gl - 1]);
        }

        f32x4 o;
        o.x = 0.5f  * (t.x + t.y);        // p2 even
        o.y = 0.25f * b[i];               // p4
        o.z = 0.5f  * (t.z + t.w);        // p2 odd
        o.w = s16 * (1.0f / 16.0f);       // f2 (k=16 pool, stride 4, clamped)
        __builtin_nontemporal_store(o, &orow[g]);
    }
}

extern "C" void kernel_launch(void* const* d_in, const int* in_sizes, int n_in,
                              void* d_out, int out_size, void* d_ws, size_t ws_size,
                              hipStream_t stream) {
    const float* x = (const float*)d_in[0];
    float* out = (float*)d_out;
    multistrike_pool_kernel<<<BA, TPB, 0, stream>>>(x, out);
}